// Round 16
// baseline (2060.988 us; speedup 1.0000x reference)
//
#include <hip/hip_runtime.h>

// LSTM (B=256, T=256, F=128, H=1024) + sigmoid + FC(1024->128).
// Persistent 256-WG x 256-thread kernel (4 waves, 1 wave/SIMD).
// R16 = R12 structure with the tile RESHAPED so W truly fits in registers:
// every prior variant demanded ~370-430 ArchVGPRs but got 216-248 -> the
// compiler re-streamed ~150 regs of W from L2 every step, serialized into
// the MFMA stream (the unexplained ~2us/step). Reshape (32rx32c)->(64rx16c):
// per-wave W 288->144 VGPRs (W ~ cols), sa 32->64 (~ rows), acc 64 (AGPR).
//
// WG (rg=wg>>6, cg=wg&63): batch rows rg*64..+64, h-cols cg*16..+16, gate
// cols {n*1024+cg*16..+16}. Output 64x64 = 4 C-tiles (mt,nt) of 32x32.
// Waves K-split (R12): wave w owns h-K [w*256,+256) (16 chunks of 16) +
// x-K [w*32,+32) (2 chunks). MFMA mfma_f32_32x32x16_f16: A row=l&31,
// k=(l>>5)*8+j; C col=l&31, row=(reg&3)+8*(reg>>2)+4*(l>>5) [m101].
// h exchange: fp8 hb[slot4][rg4][row64][col1024] (R12-proven code: byte =
// sign|f16bits(v/256)[13:7]; dq -> f16 worth v/256; W packed 256*W with
// k-perm P={0,2,1,3,4,6,5,7}; xT=x/256). Agent-scope relaxed atomics at the
// MALL; NO cache-wide maintenance. 4 rotating slots; flag transitivity WAR
// (flag[q]>=t => q's step t-3 reads done before our slot-(t+1)&3 writes).
// Sync per step (R12 flow): loads at top (slot t&3) -> compute -> direct
// coalesced h store (no hst LDS) -> __syncthreads drain -> flag t+1 ->
// per-wave poll of 16 producers. Barriers/step: 1 full + 2 LDS-only.
// Reduce: conflict-free two-stage (wave-sum float4, SoA gather).

typedef _Float16 f16x8 __attribute__((ext_vector_type(8)));
typedef float f32x16 __attribute__((ext_vector_type(16)));
typedef unsigned long long u64;
typedef unsigned u32;

#define SCOPE_AGENT __HIP_MEMORY_SCOPE_AGENT

#define WS_WP    0ull
#define WS_BIAS  9437184ull
#define WS_XT    (WS_BIAS + 16384ull)
#define WS_HB    (WS_XT + 16777216ull)          // 4 slots x 4 rg x 64KB = 1MB
#define WS_SIGH  (WS_HB + 1048576ull)
#define WS_BAR   (WS_SIGH + 1048576ull)

__device__ __forceinline__ unsigned short f2h(float f) {
  _Float16 h = (_Float16)f;
  return __builtin_bit_cast(unsigned short, h);
}
__device__ __forceinline__ float fast_sig(float x) {
  return __builtin_amdgcn_rcpf(1.f + __expf(-x));
}
__device__ __forceinline__ float fast_tanh(float x) {
  return __builtin_fmaf(2.f, fast_sig(2.f * x), -1.f);
}
__device__ __forceinline__ unsigned char h_enc(float v) {
  _Float16 gh = (_Float16)(v * 0.00390625f);
  unsigned m = __builtin_bit_cast(unsigned short, gh);
  unsigned r = m + 0x3fu + ((m >> 7) & 1u);
  return (unsigned char)(((m >> 8) & 0x80u) | ((r >> 7) & 0x7fu));
}
__device__ __forceinline__ f16x8 dq(u64 v) {
  unsigned w0 = (unsigned)v, w1 = (unsigned)(v >> 32);
  unsigned e0 = w0 & 0x00ff00ffu, o0 = (w0 >> 8) & 0x00ff00ffu;
  unsigned e1 = w1 & 0x00ff00ffu, o1 = (w1 >> 8) & 0x00ff00ffu;
  int4 t;
  t.x = (int)((e0 + (e0 & 0x00800080u)) << 7);
  t.y = (int)((o0 + (o0 & 0x00800080u)) << 7);
  t.z = (int)((e1 + (e1 & 0x00800080u)) << 7);
  t.w = (int)((o1 + (o1 & 0x00800080u)) << 7);
  return __builtin_bit_cast(f16x8, t);
}
__device__ __forceinline__ void lds_barrier() {
  asm volatile("s_waitcnt lgkmcnt(0)" ::: "memory");
  __builtin_amdgcn_s_barrier();
  asm volatile("" ::: "memory");
}

// Pack 256*W_cat into per-(cg,w,nt,q,lane) 32x32x16 MFMA B-fragments (fp16).
// i = ((((cg*4 + w)*2 + nt)*18 + q)*64 + l)*8 + j
//   u = nt*32 + (l&31); gcol = (u>>4)*1024 + cg*16 + (u&15); khi = (l>>5)*8
//   q<16 (h, PERMUTED j): k = w*256 + q*16 + khi + P[j] -> W_hh[gcol][k]
//   q>=16 (x, natural j): f = w*32 + (q-16)*16 + khi + j -> W_ih[gcol][f]
__global__ void prep_pack(const float* __restrict__ W_ih, const float* __restrict__ W_hh,
                          const float* __restrict__ b_ih, const float* __restrict__ b_hh,
                          unsigned short* __restrict__ wp, float* __restrict__ bias) {
  unsigned i = blockIdx.x * 256u + threadIdx.x;
  if (i < 4718592u) {
    unsigned j = i & 7u;
    unsigned l = (i >> 3) & 63u;
    unsigned rest = i >> 9;
    unsigned q = rest % 18u;
    unsigned rest2 = rest / 18u;
    unsigned nt = rest2 & 1u;
    unsigned rest3 = rest2 >> 1;
    unsigned w = rest3 & 3u;
    unsigned cg = rest3 >> 2;                  // 0..63
    unsigned u = nt * 32u + (l & 31u);
    unsigned gcol = (u >> 4) * 1024u + cg * 16u + (u & 15u);
    unsigned khi = (l >> 5) * 8u;
    float v;
    if (q < 16u) {
      unsigned pj = (0x75643120u >> (4u * j)) & 0xfu;   // {0,2,1,3,4,6,5,7}
      unsigned k = w * 256u + q * 16u + khi + pj;
      v = W_hh[(size_t)gcol * 1024u + k];
    } else {
      unsigned f = w * 32u + (q - 16u) * 16u + khi + j;
      v = W_ih[(size_t)gcol * 128u + f];
    }
    wp[i] = f2h(v * 256.0f);
  }
  if (i < 4096u) bias[i] = b_ih[i] + b_hh[i];
}

// xT[t][b][f] = fp16(x/256) ; h0 -> fp8 hb slot0 ; zero flags.
__global__ void prep_misc(const float* __restrict__ x, const float* __restrict__ h0,
                          unsigned short* __restrict__ xT, unsigned char* __restrict__ hb,
                          unsigned* __restrict__ bar) {
  unsigned i = blockIdx.x * 256u + threadIdx.x;
  if (i < 8388608u) {
    unsigned f = i & 127u;
    unsigned b = (i >> 7) & 255u;
    unsigned t = i >> 15;
    xT[i] = f2h(x[((size_t)b * 256u + t) * 128u + f] * 0.00390625f);
  }
  if (i < 262144u) {
    unsigned col = i & 1023u;
    unsigned grow = i >> 10;
    unsigned rg = grow >> 6;
    unsigned row = grow & 63u;
    hb[rg * 65536u + row * 1024u + col] = h_enc(h0[i]);   // slot 0
  }
  if (i < 512u) bar[i] = 0u;
}

__launch_bounds__(256, 1)
__global__ void lstm_main(const unsigned short* __restrict__ wp,
                          const float* __restrict__ bias,
                          const unsigned short* __restrict__ xT,
                          unsigned char* __restrict__ hb,
                          const float* __restrict__ c0,
                          float* __restrict__ sigh,
                          unsigned* __restrict__ bar) {
  extern __shared__ char lds[];
  // [0,64K): per-wave fp8 stage (region w*16KB: [64 rows][256B K-slice],
  //          granule-XOR swizzle (g ^ (row&15))*8)
  // [64K,128K): redv [w4][tile4][c4][l64] float4
  // [128K,144K): Sf [tile4][c4][l64] float4 (wave-summed)
  float4* redv = (float4*)(lds + 65536);
  float4* Sf4  = (float4*)(lds + 131072);
  float*  Sff  = (float*)(lds + 131072);

  const unsigned tid = threadIdx.x;
  const unsigned wg  = blockIdx.x;
  const unsigned w   = tid >> 6;
  const unsigned l   = tid & 63u;
  const unsigned rg  = wg >> 6;        // 0..3  cohort (64 rows)
  const unsigned cg  = wg & 63u;       // 0..63 col group (16 h-cols)
  const unsigned lo5 = l & 31u;
  const unsigned hi  = l >> 5;

  // ---- register-resident W fragments (36 x int4 = 144 VGPRs) ----
  int4 Braw[2][18];
  {
    const int4* wpv = (const int4*)wp;
    const unsigned wbase = (cg * 4u + w) * 2304u;   // 2*18*64 int4 per (cg,w)
#pragma unroll
    for (int nt = 0; nt < 2; ++nt)
#pragma unroll
      for (int q = 0; q < 18; ++q)
        Braw[nt][q] = wpv[wbase + (unsigned)(nt * 18 + q) * 64u + l];
  }

  // ---- cell-role addressing: thread -> (crow 0..63, hcB = 4-col base) ----
  const unsigned crow = tid >> 2;
  const unsigned hcB  = (tid & 3u) * 4u;
  float4 bias_v[4];
#pragma unroll
  for (int n = 0; n < 4; ++n)
    bias_v[n] = *(const float4*)(bias + (unsigned)n * 1024u + cg * 16u + hcB);
  const unsigned gsoff = (rg * 64u + crow) * 1024u + cg * 16u + hcB;
  float c_st[4];
  {
    float4 c4 = *(const float4*)(c0 + gsoff);
    c_st[0] = c4.x; c_st[1] = c4.y; c_st[2] = c4.z; c_st[3] = c4.w;
  }
  // cell C-gather constants: mt = crow>>5, r = crow&31
  const unsigned mt_c = crow >> 5;
  const unsigned r_c  = crow & 31u;
  const unsigned hi2  = (r_c >> 2) & 1u;
  const unsigned e_c  = (r_c & 3u) + 4u * (r_c >> 3);

  // ---- stage addressing: lane stages rows hi+2r, K-bytes w*256+lo5*8 ----
  const unsigned sgsrc0 = hi * 1024u + w * 256u + lo5 * 8u;   // + r*2048
  // frag read bases
  const unsigned frow0 = w * 16384u + lo5 * 256u;
  const unsigned frow1 = w * 16384u + (32u + lo5) * 256u;
  const unsigned fxr   = (lo5 & 15u) << 3;

  // x addressing: xr[mt][qx], f = w*32 + qx*16 + hi*8
  unsigned xoff[2][2];
#pragma unroll
  for (int mt = 0; mt < 2; ++mt)
#pragma unroll
    for (int qx = 0; qx < 2; ++qx)
      xoff[mt][qx] = ((rg * 64u + (unsigned)mt * 32u + lo5) * 128u
                      + w * 32u + (unsigned)qx * 16u + hi * 8u) * 2u;

  const char* xbase = (const char*)xT;
  char* hbase = (char*)hb;
  unsigned* flags = &bar[rg * 64u];    // 64 epoch flags per cohort

  u64 sa[32];
  int4 xr[2][2];
#pragma unroll
  for (int mt = 0; mt < 2; ++mt)
#pragma unroll
    for (int qx = 0; qx < 2; ++qx)
      xr[mt][qx] = *(const int4*)(xbase + xoff[mt][qx]);

  for (unsigned t = 0; t < 256u; ++t) {
    const bool last = (t == 255u);
    const unsigned slot = t & 3u, wslot = (t + 1u) & 3u;
    const char* hrd = hbase + slot * 262144u + rg * 65536u;
    char* hwr = hbase + wslot * 262144u + rg * 65536u;

    // ---- stage loads: 32 coalesced u64 agent loads (16KB/wave slice) ----
#pragma unroll
    for (int r = 0; r < 32; ++r)
      sa[r] = __hip_atomic_load((const u64*)(hrd + sgsrc0 + (unsigned)r * 2048u),
                                __ATOMIC_RELAXED, SCOPE_AGENT);

    f32x16 acc00 = {}, acc01 = {}, acc10 = {}, acc11 = {};
    // x chunks (fp16, no dq) while stage loads are in flight
#pragma unroll
    for (int qx = 0; qx < 2; ++qx) {
      f16x8 a0 = __builtin_bit_cast(f16x8, xr[0][qx]);
      f16x8 a1 = __builtin_bit_cast(f16x8, xr[1][qx]);
      acc00 = __builtin_amdgcn_mfma_f32_32x32x16_f16(a0, __builtin_bit_cast(f16x8, Braw[0][16 + qx]), acc00, 0, 0, 0);
      acc01 = __builtin_amdgcn_mfma_f32_32x32x16_f16(a0, __builtin_bit_cast(f16x8, Braw[1][16 + qx]), acc01, 0, 0, 0);
      acc10 = __builtin_amdgcn_mfma_f32_32x32x16_f16(a1, __builtin_bit_cast(f16x8, Braw[0][16 + qx]), acc10, 0, 0, 0);
      acc11 = __builtin_amdgcn_mfma_f32_32x32x16_f16(a1, __builtin_bit_cast(f16x8, Braw[1][16 + qx]), acc11, 0, 0, 0);
    }

    // ---- stage write to own LDS region (granule XOR (row&15)) ----
#pragma unroll
    for (int r = 0; r < 32; ++r) {
      unsigned rr = hi + 2u * (unsigned)r;
      unsigned d = w * 16384u + rr * 256u + ((lo5 * 8u) ^ ((rr & 15u) << 3));
      *(u64*)(lds + d) = sa[r];
    }
    asm volatile("s_waitcnt lgkmcnt(0)" ::: "memory");

    // ---- 16 h chunks: 2 dq + 4 MFMA each ----
#pragma unroll
    for (int q = 0; q < 16; ++q) {
      unsigned kb = ((unsigned)q * 16u + hi * 8u);
      f16x8 a0 = dq(*(const u64*)(lds + frow0 + (kb ^ fxr)));
      f16x8 a1 = dq(*(const u64*)(lds + frow1 + (kb ^ fxr)));
      acc00 = __builtin_amdgcn_mfma_f32_32x32x16_f16(a0, __builtin_bit_cast(f16x8, Braw[0][q]), acc00, 0, 0, 0);
      acc01 = __builtin_amdgcn_mfma_f32_32x32x16_f16(a0, __builtin_bit_cast(f16x8, Braw[1][q]), acc01, 0, 0, 0);
      acc10 = __builtin_amdgcn_mfma_f32_32x32x16_f16(a1, __builtin_bit_cast(f16x8, Braw[0][q]), acc10, 0, 0, 0);
      acc11 = __builtin_amdgcn_mfma_f32_32x32x16_f16(a1, __builtin_bit_cast(f16x8, Braw[1][q]), acc11, 0, 0, 0);
    }

    // ---- reduce: write partials (tile = mt*2+nt) ----
#pragma unroll
    for (int c = 0; c < 4; ++c) {
      float4 v0; v0.x = acc00[4*c]; v0.y = acc00[4*c+1]; v0.z = acc00[4*c+2]; v0.w = acc00[4*c+3];
      float4 v1; v1.x = acc01[4*c]; v1.y = acc01[4*c+1]; v1.z = acc01[4*c+2]; v1.w = acc01[4*c+3];
      float4 v2; v2.x = acc10[4*c]; v2.y = acc10[4*c+1]; v2.z = acc10[4*c+2]; v2.w = acc10[4*c+3];
      float4 v3; v3.x = acc11[4*c]; v3.y = acc11[4*c+1]; v3.z = acc11[4*c+2]; v3.w = acc11[4*c+3];
      redv[((w * 4u + 0u) * 4u + (unsigned)c) * 64u + l] = v0;
      redv[((w * 4u + 1u) * 4u + (unsigned)c) * 64u + l] = v1;
      redv[((w * 4u + 2u) * 4u + (unsigned)c) * 64u + l] = v2;
      redv[((w * 4u + 3u) * 4u + (unsigned)c) * 64u + l] = v3;
    }
    __syncthreads();

    // ---- stage-1: wave w sums tile w across waves (conflict-free) ----
#pragma unroll
    for (int c = 0; c < 4; ++c) {
      float4 s = redv[((0u * 4u + w) * 4u + (unsigned)c) * 64u + l];
#pragma unroll
      for (int wo = 1; wo < 4; ++wo) {
        float4 v = redv[(((unsigned)wo * 4u + w) * 4u + (unsigned)c) * 64u + l];
        s.x += v.x; s.y += v.y; s.z += v.z; s.w += v.w;
      }
      Sf4[(w * 4u + (unsigned)c) * 64u + l] = s;
    }
    lds_barrier();

    // ---- stage-2 gather + cell (thread = crow, hcB) ----
    u32 pk = 0u;
#pragma unroll
    for (int p = 0; p < 4; ++p) {
      float gv[4];
#pragma unroll
      for (int n = 0; n < 4; ++n) {
        unsigned u = (unsigned)n * 16u + hcB + (unsigned)p;
        unsigned tile = mt_c * 2u + (u >> 5);
        unsigned l2 = (u & 31u) + 32u * hi2;
        gv[n] = Sff[((tile * 4u + (e_c >> 2)) * 64u + l2) * 4u + (e_c & 3u)];
      }
      float ig = fast_sig(gv[0] + ((const float*)&bias_v[0])[p]);
      float fg = fast_sig(gv[1] + ((const float*)&bias_v[1])[p]);
      float gg = fast_tanh(gv[2] + ((const float*)&bias_v[2])[p]);
      float og = fast_sig(gv[3] + ((const float*)&bias_v[3])[p]);
      float cc = fg * c_st[p] + ig * gg;
      c_st[p] = cc;
      float hhv = og * fast_tanh(cc);
      pk |= (u32)h_enc(hhv) << (8 * p);
      if (last) sigh[gsoff + (unsigned)p] = fast_sig(hhv);
    }

    if (!last) {
      // ---- direct coalesced h store: 256 threads x 4B ----
      __hip_atomic_store((u32*)(hwr + crow * 1024u + cg * 16u + hcB), pk,
                         __ATOMIC_RELAXED, SCOPE_AGENT);
      // x prefetch for t+1
#pragma unroll
      for (int mt = 0; mt < 2; ++mt)
#pragma unroll
        for (int qx = 0; qx < 2; ++qx)
          xr[mt][qx] = *(const int4*)(xbase + xoff[mt][qx] + (t + 1u) * 65536u);
      // drain (vmcnt0 in barrier lowering): h stores ACKed at the MALL
      __syncthreads();
      if (tid == 0)
        __hip_atomic_store(&flags[cg], t + 1u, __ATOMIC_RELAXED, SCOPE_AGENT);
      // per-wave poll: this wave's 16 producers (cg' in [16w,16w+16))
      {
        const unsigned tgt = t + 1u;
        const unsigned fidx = w * 16u + (l & 15u);
        for (;;) {
          unsigned f = __hip_atomic_load(&flags[fidx], __ATOMIC_RELAXED, SCOPE_AGENT);
          if (__all(l >= 16u || f >= tgt)) break;
          __builtin_amdgcn_s_sleep(1);
        }
      }
    }
  }
}

// out[b][o] = b_fc[o] + sum_k sigh[b][k] * W_fc[o][k]
__global__ void final_fc(const float* __restrict__ sigh, const float* __restrict__ W_fc,
                         const float* __restrict__ b_fc, float* __restrict__ out) {
  unsigned b = blockIdx.x;
  unsigned o = threadIdx.x;
  const float* hrow = sigh + (size_t)b * 1024u;
  const float* wrow = W_fc + (size_t)o * 1024u;
  float acc = b_fc[o];
#pragma unroll 8
  for (unsigned k = 0; k < 1024u; k += 4u) {
    float4 hv = *(const float4*)(hrow + k);
    float4 wv = *(const float4*)(wrow + k);
    acc += hv.x * wv.x + hv.y * wv.y + hv.z * wv.z + hv.w * wv.w;
  }
  out[b * 128u + o] = acc;
}

extern "C" void kernel_launch(void* const* d_in, const int* in_sizes, int n_in,
                              void* d_out, int out_size, void* d_ws, size_t ws_size,
                              hipStream_t stream) {
  (void)in_sizes; (void)n_in; (void)out_size; (void)ws_size;
  const float* x    = (const float*)d_in[0];
  const float* h0   = (const float*)d_in[1];
  const float* c0   = (const float*)d_in[2];
  const float* W_ih = (const float*)d_in[3];
  const float* W_hh = (const float*)d_in[4];
  const float* b_ih = (const float*)d_in[5];
  const float* b_hh = (const float*)d_in[6];
  const float* W_fc = (const float*)d_in[7];
  const float* b_fc = (const float*)d_in[8];

  char* ws = (char*)d_ws;
  unsigned short* wp   = (unsigned short*)(ws + WS_WP);
  float*          bias = (float*)(ws + WS_BIAS);
  unsigned short* xT   = (unsigned short*)(ws + WS_XT);
  unsigned char*  hb   = (unsigned char*)(ws + WS_HB);
  float*          sigh = (float*)(ws + WS_SIGH);
  unsigned*       bar  = (unsigned*)(ws + WS_BAR);
  float*          out  = (float*)d_out;

  prep_pack<<<18432, 256, 0, stream>>>(W_ih, W_hh, b_ih, b_hh, wp, bias);
  prep_misc<<<32768, 256, 0, stream>>>(x, h0, xT, hb, bar);
  lstm_main<<<256, 256, 147456, stream>>>(wp, bias, xT, hb, c0, sigh, bar);
  final_fc<<<256, 128, 0, stream>>>(sigh, W_fc, b_fc, out);
}